// Round 18
// baseline (2434.239 us; speedup 1.0000x reference)
//
#include <hip/hip_runtime.h>
#include <math.h>

// Residual VQ: x (262144,128) fp32, codebooks (3,256,128) fp32.
// Output: [indices as float (262144*3)] ++ [quantized (262144*128)].
//
// ARITHMETIC CONTRACT (absmax=0 — do not change):
//   M_k  = OpenBLAS sgemm K-loop: sequential FMA chain j=0..127, acc init 0
//   A    = np.sum(r*r): pairwise_sum 8-accumulator scheme, products rounded
//          separately (fmaf(x,x,0) = single-rounded product, blocks fusion)
//   d2_k = (A - 2.0f*M_k) + B_k ; argmin strict < ascending k == first-min
//          (per-lane v-ascending strict-<, then (val,idx) shuffle-reduce
//           with tie -> smaller idx: identical semantics)
//   residual: r1 = x - q0, r2 = r1 - q1 — in-place global scratch, ref order
//   quantized = (q0 + q1) + q2 elementwise fp32, ref order
//
// ROUND 22 CHANGE: r21's reg double-buffer hit the 128-VGPR cap and spilled
// (FETCH/WRITE +75MB each, busy 532->646us) — reverted to r20. New insight
// from the session's occupancy series: OccupancyPercent ~= 11% x the
// launch_bounds 2nd arg across ALL eight configs (2->22, 3->33, 4->44,
// 5->53, 6->61), INDEPENDENT of VGPR usage — r20's VGPR=108 permits 4
// waves/SIMD (50%) but at hint 2 it runs ~1.8. The hint pins achieved
// residency (~0.9x hint waves/SIMD) while also capping VGPRs at
// ~512/(2*hint). These are two knobs; r20 runs at HALF its register-allowed
// residency. Fix: REMOVE __launch_bounds__ entirely (never tested this
// session). Compiler allocates by its own no-spill heuristic (~108-140 for
// this working set); scheduler fills waves by actual resources -> ~4
// waves/SIMD = 2x stall coverage for this latency-bound kernel. Source
// otherwise r20 verbatim (verified absmax=0).

constexpr int kItems = 262144;
constexpr int kDim   = 128;
constexpr int kNcb   = 3;
constexpr int kK     = 256;
constexpr int kBlock = 256;
constexpr int kBatch = 16;        // items per wave (wave-private batch)
constexpr int NPH    = 32;        // phases of 4 dims

__device__ __forceinline__ float sq_rn(float x) {
    return __builtin_fmaf(x, x, 0.0f);
}

// numpy pairwise_sum, n=128 (for the B-table)
template <typename F>
__device__ __forceinline__ float np_pairwise128(F term) {
    float r0 = term(0), r1 = term(1), r2 = term(2), r3 = term(3),
          r4 = term(4), r5 = term(5), r6 = term(6), r7 = term(7);
    #pragma unroll
    for (int i = 8; i < 128; i += 8) {
        r0 = r0 + term(i + 0); r1 = r1 + term(i + 1);
        r2 = r2 + term(i + 2); r3 = r3 + term(i + 3);
        r4 = r4 + term(i + 4); r5 = r5 + term(i + 5);
        r6 = r6 + term(i + 6); r7 = r7 + term(i + 7);
    }
    return ((r0 + r1) + (r2 + r3)) + ((r4 + r5) + (r6 + r7));
}

// ---------- pre-kernel: Bt (768 floats) + transposed codebook cbT:
// cbT[(c*128 + j)*256 + e] = cb[(c*256 + e)*128 + j]
__global__ void rvq_prep(const float* __restrict__ cb,
                         float* __restrict__ Bt,
                         float* __restrict__ cbT)
{
    const int tid = blockIdx.x * 256 + threadIdx.x;   // 384*256 = 98304
    const int e = tid & 255;
    const int j = (tid >> 8) & 127;
    const int c = tid >> 15;
    cbT[tid] = cb[((size_t)c * kK + e) * kDim + j];
    if (tid < kNcb * kK) {
        const float* row = cb + (size_t)tid * kDim;
        Bt[tid] = np_pairwise128([&](int jj) { return sq_rn(row[jj]); });
    }
}

#define X16(X) X(0) X(1) X(2) X(3) X(4) X(5) X(6) X(7) \
  X(8) X(9) X(10) X(11) X(12) X(13) X(14) X(15)

#define MDECL(i) float m##i##_0 = 0.f, m##i##_1 = 0.f, \
                       m##i##_2 = 0.f, m##i##_3 = 0.f;

// one item's phase step: broadcast residual float4 (same addr all lanes),
// 16 FMAs; per-acc chain = d ascending within phase, phases ascending -> j
// = 0..127 sequential (OpenBLAS K-loop order, bit-exact)
#define MITEM(i) { \
    const float4 rv = *(const float4*)(rb_ + (size_t)(i) * kDim + 4 * p); \
    m##i##_0 = __builtin_fmaf(rv.x, cb0_0, m##i##_0); \
    m##i##_0 = __builtin_fmaf(rv.y, cb1_0, m##i##_0); \
    m##i##_0 = __builtin_fmaf(rv.z, cb2_0, m##i##_0); \
    m##i##_0 = __builtin_fmaf(rv.w, cb3_0, m##i##_0); \
    m##i##_1 = __builtin_fmaf(rv.x, cb0_1, m##i##_1); \
    m##i##_1 = __builtin_fmaf(rv.y, cb1_1, m##i##_1); \
    m##i##_1 = __builtin_fmaf(rv.z, cb2_1, m##i##_1); \
    m##i##_1 = __builtin_fmaf(rv.w, cb3_1, m##i##_1); \
    m##i##_2 = __builtin_fmaf(rv.x, cb0_2, m##i##_2); \
    m##i##_2 = __builtin_fmaf(rv.y, cb1_2, m##i##_2); \
    m##i##_2 = __builtin_fmaf(rv.z, cb2_2, m##i##_2); \
    m##i##_2 = __builtin_fmaf(rv.w, cb3_2, m##i##_2); \
    m##i##_3 = __builtin_fmaf(rv.x, cb0_3, m##i##_3); \
    m##i##_3 = __builtin_fmaf(rv.y, cb1_3, m##i##_3); \
    m##i##_3 = __builtin_fmaf(rv.z, cb2_3, m##i##_3); \
    m##i##_3 = __builtin_fmaf(rv.w, cb3_3, m##i##_3); }

// d2 + argmin for item i: per-lane candidates v ascending (strict < keeps
// lowest idx), then 6-step (val,idx) butterfly reduce, tie -> smaller idx
// == numpy first-min over all 256 entries
#define ARGMIN(i) { \
    const float Ai = __shfl(Areg, (i)); \
    float bv = __builtin_fmaf(-2.0f, m##i##_0, Ai) + B0; \
    int   bx = lane; \
    float dd = __builtin_fmaf(-2.0f, m##i##_1, Ai) + B1; \
    if (dd < bv) { bv = dd; bx = 64 + lane; } \
    dd = __builtin_fmaf(-2.0f, m##i##_2, Ai) + B2; \
    if (dd < bv) { bv = dd; bx = 128 + lane; } \
    dd = __builtin_fmaf(-2.0f, m##i##_3, Ai) + B3; \
    if (dd < bv) { bv = dd; bx = 192 + lane; } \
    _Pragma("unroll") \
    for (int off = 32; off; off >>= 1) { \
        const float ov = __shfl_xor(bv, off); \
        const int   ox = __shfl_xor(bx, off); \
        const bool take = (ov < bv) || (ov == bv && ox < bx); \
        bv = take ? ov : bv; bx = take ? ox : bx; \
    } \
    if (c == 0)      sel0 = (lane == (i)) ? bx : sel0; \
    else if (c == 1) sel1 = (lane == (i)) ? bx : sel1; \
    else             sel2 = (lane == (i)) ? bx : sel2; }

__global__ void rvq_kernel(
    const float* __restrict__ x,
    const float* __restrict__ cb,
    const float* __restrict__ Bt,
    const float* __restrict__ cbT,
    float* __restrict__ out)
{
    const int t = threadIdx.x;
    const int lane = t & 63;
    // global wave id = batch id; each wave fully independent (no LDS, no bar)
    const int wid = blockIdx.x * (kBlock / 64) + (t >> 6);
    const size_t ibase = (size_t)wid * kBatch;

    float* out_idx = out;                             // (items, 3) as float
    float* out_q   = out + (size_t)kItems * kNcb;     // (items, 128)

    const float* xb = x + ibase * kDim;               // batch x rows
    float*       qb = out_q + ibase * kDim;           // batch scratch rows

    int sel0 = 0, sel1 = 0, sel2 = 0;                 // lane i: item i's sel

    #pragma unroll 1
    for (int c = 0; c < kNcb; ++c) {
        const float* rb_ = (c == 0) ? xb : (const float*)qb;
        const float* cbTc = cbT + (size_t)c * kDim * kK;

        // ---- A: lane i computes item i's np.sum(r*r), 8-stripe pairwise
        float Areg = 0.0f;
        if (lane < kBatch) {
            const float4* rr = (const float4*)(rb_ + (size_t)lane * kDim);
            float4 ra = rr[0], rb2 = rr[1];
            float a0 = sq_rn(ra.x),  a1 = sq_rn(ra.y),
                  a2 = sq_rn(ra.z),  a3 = sq_rn(ra.w),
                  a4 = sq_rn(rb2.x), a5 = sq_rn(rb2.y),
                  a6 = sq_rn(rb2.z), a7 = sq_rn(rb2.w);
            #pragma unroll
            for (int g = 1; g < 16; ++g) {
                ra = rr[2 * g]; rb2 = rr[2 * g + 1];
                a0 = a0 + sq_rn(ra.x);  a1 = a1 + sq_rn(ra.y);
                a2 = a2 + sq_rn(ra.z);  a3 = a3 + sq_rn(ra.w);
                a4 = a4 + sq_rn(rb2.x); a5 = a5 + sq_rn(rb2.y);
                a6 = a6 + sq_rn(rb2.z); a7 = a7 + sq_rn(rb2.w);
            }
            Areg = ((a0 + a1) + (a2 + a3)) + ((a4 + a5) + (a6 + a7));
        }

        // ---- M: 64 accs (16 items x 4 entry-groups), codebook in VGPRs
        X16(MDECL)
        #pragma unroll 1
        for (int p = 0; p < NPH; ++p) {
            const float* cbp = cbTc + (size_t)(4 * p) * kK + lane;
            const float cb0_0 = cbp[0],   cb0_1 = cbp[64],
                        cb0_2 = cbp[128], cb0_3 = cbp[192];
            const float cb1_0 = cbp[256], cb1_1 = cbp[320],
                        cb1_2 = cbp[384], cb1_3 = cbp[448];
            const float cb2_0 = cbp[512], cb2_1 = cbp[576],
                        cb2_2 = cbp[640], cb2_3 = cbp[704];
            const float cb3_0 = cbp[768], cb3_1 = cbp[832],
                        cb3_2 = cbp[896], cb3_3 = cbp[960];
            X16(MITEM)
        }

        // ---- argmin (B per-lane, coalesced)
        const float* Btc = Bt + c * kK;
        const float B0 = Btc[lane],       B1 = Btc[64 + lane];
        const float B2 = Btc[128 + lane], B3 = Btc[192 + lane];
        X16(ARGMIN)

        // ---- residual update into wave-private scratch rows
        if (c < 2) {
            #pragma unroll 1
            for (int i = 0; i < kBatch; ++i) {
                const int s = __shfl((c == 0) ? sel0 : sel1, i);
                const float* cwrow = cb + ((size_t)c * kK + s) * kDim;
                const float2 w = *(const float2*)(cwrow + 2 * lane);
                float* dr = qb + (size_t)i * kDim;
                const float* sr = (c == 0) ? (xb + (size_t)i * kDim)
                                           : (const float*)dr;
                float2 rv = *(const float2*)(sr + 2 * lane);
                rv.x = rv.x - w.x;             // one rounding each, ref order
                rv.y = rv.y - w.y;
                *(float2*)(dr + 2 * lane) = rv;
            }
            // scratch writes must be visible to this wave's next-cb loads
            asm volatile("s_waitcnt vmcnt(0)" ::: "memory");
        }
    }

    // ---- outputs: quantized (overwrites scratch; all r2 reads done) + idx
    #pragma unroll 1
    for (int i = 0; i < kBatch; ++i) {
        const int s0 = __shfl(sel0, i);
        const int s1 = __shfl(sel1, i);
        const int s2 = __shfl(sel2, i);
        const float2 u = *(const float2*)(cb + ((size_t)0 * kK + s0) * kDim + 2 * lane);
        const float2 v = *(const float2*)(cb + ((size_t)1 * kK + s1) * kDim + 2 * lane);
        const float2 w = *(const float2*)(cb + ((size_t)2 * kK + s2) * kDim + 2 * lane);
        float2 o;
        o.x = (u.x + v.x) + w.x;               // ((0+q0)+q1)+q2, ref order
        o.y = (u.y + v.y) + w.y;
        *(float2*)(qb + (size_t)i * kDim + 2 * lane) = o;
        if (lane == 0) {
            out_idx[(ibase + i) * kNcb + 0] = (float)s0;
            out_idx[(ibase + i) * kNcb + 1] = (float)s1;
            out_idx[(ibase + i) * kNcb + 2] = (float)s2;
        }
    }
}

extern "C" void kernel_launch(void* const* d_in, const int* in_sizes, int n_in,
                              void* d_out, int out_size, void* d_ws, size_t ws_size,
                              hipStream_t stream) {
    const float* x  = (const float*)d_in[0];
    const float* cb = (const float*)d_in[1];
    float* out = (float*)d_out;
    float* Bt  = (float*)d_ws;                 // 768 floats
    float* cbT = (float*)d_ws + 1024;          // 98304 floats (384 KB)
    rvq_prep<<<384, 256, 0, stream>>>(cb, Bt, cbT);
    // 16384 waves (one 16-item batch each) = 4096 blocks x 4 waves
    rvq_kernel<<<kItems / (kBatch * 4), kBlock, 0, stream>>>(x, cb, Bt, cbT, out);
}

// Round 19
// 1793.461 us; speedup vs baseline: 1.3573x; 1.3573x over previous
//
#include <hip/hip_runtime.h>
#include <math.h>

// Residual VQ: x (262144,128) fp32, codebooks (3,256,128) fp32.
// Output: [indices as float (262144*3)] ++ [quantized (262144*128)].
//
// ARITHMETIC CONTRACT (absmax=0 — do not change):
//   M_k  = OpenBLAS sgemm K-loop: sequential FMA chain j=0..127, acc init 0
//   A    = np.sum(r*r): pairwise_sum 8-accumulator scheme, products rounded
//          separately (fmaf(x,x,0) = single-rounded product, blocks fusion)
//   d2_k = (A - 2.0f*M_k) + B_k ; argmin strict < ascending k == first-min
//          (per-lane v-ascending strict-<, then (val,idx) shuffle-reduce
//           with tie -> smaller idx: identical semantics)
//   residual: r1 = x - q0, r2 = r1 - q1 — in-place global scratch, ref order
//   quantized = (q0 + q1) + q2 elementwise fp32, ref order
//
// ROUND 23 CHANGE: r22 (no launch_bounds) proved the compiler's DEFAULT
// register target is 64 VGPRs -> catastrophic spill (WRITE 4.3GB, 2434us).
// Full map: hint N -> cap ~512/2N; no hint -> 64. r21's double-buffer failed
// ONLY because it collided with hint 2's cap of 128 (VGPR pinned at exactly
// 128 = silent spill). And hint 1 achieves the SAME residency as hint 2
// (rounds 0/1: 23.8% vs r20's 22% — actual VGPR usage limits residency, not
// the hint) while raising the cap to 256. So: r21's u/v ping-pong register
// double-buffer (+16 VGPR, eliminates the per-phase codebook-load latency
// exposure that r20's 40% duty identified: 16 loads consumed by the phase's
// FIRST FMA -> ~300cyc exposed per 512cyc phase) + __launch_bounds__(256,1)
// (cap 256, expected usage ~140, 110 regs of headroom -> no spill pressure).
// Prefetch changes timing only — same loads, chains, rounding (verified
// absmax=0 in r20/r21).

constexpr int kItems = 262144;
constexpr int kDim   = 128;
constexpr int kNcb   = 3;
constexpr int kK     = 256;
constexpr int kBlock = 256;
constexpr int kBatch = 16;        // items per wave (wave-private batch)
constexpr int NPH    = 32;        // phases of 4 dims

__device__ __forceinline__ float sq_rn(float x) {
    return __builtin_fmaf(x, x, 0.0f);
}

// numpy pairwise_sum, n=128 (for the B-table)
template <typename F>
__device__ __forceinline__ float np_pairwise128(F term) {
    float r0 = term(0), r1 = term(1), r2 = term(2), r3 = term(3),
          r4 = term(4), r5 = term(5), r6 = term(6), r7 = term(7);
    #pragma unroll
    for (int i = 8; i < 128; i += 8) {
        r0 = r0 + term(i + 0); r1 = r1 + term(i + 1);
        r2 = r2 + term(i + 2); r3 = r3 + term(i + 3);
        r4 = r4 + term(i + 4); r5 = r5 + term(i + 5);
        r6 = r6 + term(i + 6); r7 = r7 + term(i + 7);
    }
    return ((r0 + r1) + (r2 + r3)) + ((r4 + r5) + (r6 + r7));
}

// ---------- pre-kernel: Bt (768 floats) + transposed codebook cbT:
// cbT[(c*128 + j)*256 + e] = cb[(c*256 + e)*128 + j]
__global__ void rvq_prep(const float* __restrict__ cb,
                         float* __restrict__ Bt,
                         float* __restrict__ cbT)
{
    const int tid = blockIdx.x * 256 + threadIdx.x;   // 384*256 = 98304
    const int e = tid & 255;
    const int j = (tid >> 8) & 127;
    const int c = tid >> 15;
    cbT[tid] = cb[((size_t)c * kK + e) * kDim + j];
    if (tid < kNcb * kK) {
        const float* row = cb + (size_t)tid * kDim;
        Bt[tid] = np_pairwise128([&](int jj) { return sq_rn(row[jj]); });
    }
}

#define X16(X) X(0) X(1) X(2) X(3) X(4) X(5) X(6) X(7) \
  X(8) X(9) X(10) X(11) X(12) X(13) X(14) X(15)

#define MDECL(i) float m##i##_0 = 0.f, m##i##_1 = 0.f, \
                       m##i##_2 = 0.f, m##i##_3 = 0.f;

// declare one 16-reg codebook tile set with prefix R
#define CBSET(R) float R##0_0, R##0_1, R##0_2, R##0_3, \
                       R##1_0, R##1_1, R##1_2, R##1_3, \
                       R##2_0, R##2_1, R##2_2, R##2_3, \
                       R##3_0, R##3_1, R##3_2, R##3_3;

// load phase PH's 16 transposed-codebook values into set R (per-lane dwords)
#define CBLOAD(R, PH) { \
    const float* cbp_ = cbTc + (size_t)(4 * (PH)) * kK + lane; \
    R##0_0 = cbp_[0];   R##0_1 = cbp_[64];  R##0_2 = cbp_[128]; R##0_3 = cbp_[192]; \
    R##1_0 = cbp_[256]; R##1_1 = cbp_[320]; R##1_2 = cbp_[384]; R##1_3 = cbp_[448]; \
    R##2_0 = cbp_[512]; R##2_1 = cbp_[576]; R##2_2 = cbp_[640]; R##2_3 = cbp_[704]; \
    R##3_0 = cbp_[768]; R##3_1 = cbp_[832]; R##3_2 = cbp_[896]; R##3_3 = cbp_[960]; }

// one item's phase step on tile set R at phase P: broadcast residual float4
// (same addr all lanes), 16 FMAs; per-acc chain = d ascending within phase,
// phases ascending -> j = 0..127 sequential (OpenBLAS K order, bit-exact)
#define MITEM(i, R, P) { \
    const float4 rv = *(const float4*)(rb_ + (size_t)(i) * kDim + 4 * (P)); \
    m##i##_0 = __builtin_fmaf(rv.x, R##0_0, m##i##_0); \
    m##i##_0 = __builtin_fmaf(rv.y, R##1_0, m##i##_0); \
    m##i##_0 = __builtin_fmaf(rv.z, R##2_0, m##i##_0); \
    m##i##_0 = __builtin_fmaf(rv.w, R##3_0, m##i##_0); \
    m##i##_1 = __builtin_fmaf(rv.x, R##0_1, m##i##_1); \
    m##i##_1 = __builtin_fmaf(rv.y, R##1_1, m##i##_1); \
    m##i##_1 = __builtin_fmaf(rv.z, R##2_1, m##i##_1); \
    m##i##_1 = __builtin_fmaf(rv.w, R##3_1, m##i##_1); \
    m##i##_2 = __builtin_fmaf(rv.x, R##0_2, m##i##_2); \
    m##i##_2 = __builtin_fmaf(rv.y, R##1_2, m##i##_2); \
    m##i##_2 = __builtin_fmaf(rv.z, R##2_2, m##i##_2); \
    m##i##_2 = __builtin_fmaf(rv.w, R##3_2, m##i##_2); \
    m##i##_3 = __builtin_fmaf(rv.x, R##0_3, m##i##_3); \
    m##i##_3 = __builtin_fmaf(rv.y, R##1_3, m##i##_3); \
    m##i##_3 = __builtin_fmaf(rv.z, R##2_3, m##i##_3); \
    m##i##_3 = __builtin_fmaf(rv.w, R##3_3, m##i##_3); }

#define MITEMS_U(P) \
    MITEM(0,u,P) MITEM(1,u,P) MITEM(2,u,P) MITEM(3,u,P) \
    MITEM(4,u,P) MITEM(5,u,P) MITEM(6,u,P) MITEM(7,u,P) \
    MITEM(8,u,P) MITEM(9,u,P) MITEM(10,u,P) MITEM(11,u,P) \
    MITEM(12,u,P) MITEM(13,u,P) MITEM(14,u,P) MITEM(15,u,P)
#define MITEMS_V(P) \
    MITEM(0,v,P) MITEM(1,v,P) MITEM(2,v,P) MITEM(3,v,P) \
    MITEM(4,v,P) MITEM(5,v,P) MITEM(6,v,P) MITEM(7,v,P) \
    MITEM(8,v,P) MITEM(9,v,P) MITEM(10,v,P) MITEM(11,v,P) \
    MITEM(12,v,P) MITEM(13,v,P) MITEM(14,v,P) MITEM(15,v,P)

// d2 + argmin for item i (strict <, v ascending, then butterfly; tie ->
// smaller idx == numpy first-min over all 256 entries)
#define ARGMIN(i) { \
    const float Ai = __shfl(Areg, (i)); \
    float bv = __builtin_fmaf(-2.0f, m##i##_0, Ai) + B0; \
    int   bx = lane; \
    float dd = __builtin_fmaf(-2.0f, m##i##_1, Ai) + B1; \
    if (dd < bv) { bv = dd; bx = 64 + lane; } \
    dd = __builtin_fmaf(-2.0f, m##i##_2, Ai) + B2; \
    if (dd < bv) { bv = dd; bx = 128 + lane; } \
    dd = __builtin_fmaf(-2.0f, m##i##_3, Ai) + B3; \
    if (dd < bv) { bv = dd; bx = 192 + lane; } \
    _Pragma("unroll") \
    for (int off = 32; off; off >>= 1) { \
        const float ov = __shfl_xor(bv, off); \
        const int   ox = __shfl_xor(bx, off); \
        const bool take = (ov < bv) || (ov == bv && ox < bx); \
        bv = take ? ov : bv; bx = take ? ox : bx; \
    } \
    if (c == 0)      sel0 = (lane == (i)) ? bx : sel0; \
    else if (c == 1) sel1 = (lane == (i)) ? bx : sel1; \
    else             sel2 = (lane == (i)) ? bx : sel2; }

__global__ __launch_bounds__(kBlock, 1) void rvq_kernel(
    const float* __restrict__ x,
    const float* __restrict__ cb,
    const float* __restrict__ Bt,
    const float* __restrict__ cbT,
    float* __restrict__ out)
{
    const int t = threadIdx.x;
    const int lane = t & 63;
    // global wave id = batch id; each wave fully independent (no LDS, no bar)
    const int wid = blockIdx.x * (kBlock / 64) + (t >> 6);
    const size_t ibase = (size_t)wid * kBatch;

    float* out_idx = out;                             // (items, 3) as float
    float* out_q   = out + (size_t)kItems * kNcb;     // (items, 128)

    const float* xb = x + ibase * kDim;               // batch x rows
    float*       qb = out_q + ibase * kDim;           // batch scratch rows

    int sel0 = 0, sel1 = 0, sel2 = 0;                 // lane i: item i's sel

    #pragma unroll 1
    for (int c = 0; c < kNcb; ++c) {
        const float* rb_ = (c == 0) ? xb : (const float*)qb;
        const float* cbTc = cbT + (size_t)c * kDim * kK;

        // ---- A: lane i computes item i's np.sum(r*r), 8-stripe pairwise
        float Areg = 0.0f;
        if (lane < kBatch) {
            const float4* rr = (const float4*)(rb_ + (size_t)lane * kDim);
            float4 ra = rr[0], rb2 = rr[1];
            float a0 = sq_rn(ra.x),  a1 = sq_rn(ra.y),
                  a2 = sq_rn(ra.z),  a3 = sq_rn(ra.w),
                  a4 = sq_rn(rb2.x), a5 = sq_rn(rb2.y),
                  a6 = sq_rn(rb2.z), a7 = sq_rn(rb2.w);
            #pragma unroll
            for (int g = 1; g < 16; ++g) {
                ra = rr[2 * g]; rb2 = rr[2 * g + 1];
                a0 = a0 + sq_rn(ra.x);  a1 = a1 + sq_rn(ra.y);
                a2 = a2 + sq_rn(ra.z);  a3 = a3 + sq_rn(ra.w);
                a4 = a4 + sq_rn(rb2.x); a5 = a5 + sq_rn(rb2.y);
                a6 = a6 + sq_rn(rb2.z); a7 = a7 + sq_rn(rb2.w);
            }
            Areg = ((a0 + a1) + (a2 + a3)) + ((a4 + a5) + (a6 + a7));
        }

        // ---- M: 64 accs (16 items x 4 entry-groups); codebook tile
        // double-buffered in registers (u/v ping-pong, no movs)
        X16(MDECL)
        CBSET(u)
        CBSET(v)
        CBLOAD(u, 0)
        #pragma unroll 1
        for (int pp = 0; pp < NPH / 2 - 1; ++pp) {      // phases 0..29
            CBLOAD(v, 2 * pp + 1)                       // prefetch odd phase
            MITEMS_U(2 * pp)                            // compute even phase
            CBLOAD(u, 2 * pp + 2)                       // prefetch next even
            MITEMS_V(2 * pp + 1)                        // compute odd phase
        }
        CBLOAD(v, NPH - 1)                              // phase 31
        MITEMS_U(NPH - 2)                               // phase 30
        MITEMS_V(NPH - 1)                               // phase 31

        // ---- argmin (B per-lane, coalesced)
        const float* Btc = Bt + c * kK;
        const float B0 = Btc[lane],       B1 = Btc[64 + lane];
        const float B2 = Btc[128 + lane], B3 = Btc[192 + lane];
        X16(ARGMIN)

        // ---- residual update into wave-private scratch rows
        if (c < 2) {
            #pragma unroll 1
            for (int i = 0; i < kBatch; ++i) {
                const int s = __shfl((c == 0) ? sel0 : sel1, i);
                const float* cwrow = cb + ((size_t)c * kK + s) * kDim;
                const float2 w = *(const float2*)(cwrow + 2 * lane);
                float* dr = qb + (size_t)i * kDim;
                const float* sr = (c == 0) ? (xb + (size_t)i * kDim)
                                           : (const float*)dr;
                float2 rv = *(const float2*)(sr + 2 * lane);
                rv.x = rv.x - w.x;             // one rounding each, ref order
                rv.y = rv.y - w.y;
                *(float2*)(dr + 2 * lane) = rv;
            }
            // scratch writes must be visible to this wave's next-cb loads
            asm volatile("s_waitcnt vmcnt(0)" ::: "memory");
        }
    }

    // ---- outputs: quantized (overwrites scratch; all r2 reads done) + idx
    #pragma unroll 1
    for (int i = 0; i < kBatch; ++i) {
        const int s0 = __shfl(sel0, i);
        const int s1 = __shfl(sel1, i);
        const int s2 = __shfl(sel2, i);
        const float2 u = *(const float2*)(cb + ((size_t)0 * kK + s0) * kDim + 2 * lane);
        const float2 v = *(const float2*)(cb + ((size_t)1 * kK + s1) * kDim + 2 * lane);
        const float2 w = *(const float2*)(cb + ((size_t)2 * kK + s2) * kDim + 2 * lane);
        float2 o;
        o.x = (u.x + v.x) + w.x;               // ((0+q0)+q1)+q2, ref order
        o.y = (u.y + v.y) + w.y;
        *(float2*)(qb + (size_t)i * kDim + 2 * lane) = o;
        if (lane == 0) {
            out_idx[(ibase + i) * kNcb + 0] = (float)s0;
            out_idx[(ibase + i) * kNcb + 1] = (float)s1;
            out_idx[(ibase + i) * kNcb + 2] = (float)s2;
        }
    }
}

extern "C" void kernel_launch(void* const* d_in, const int* in_sizes, int n_in,
                              void* d_out, int out_size, void* d_ws, size_t ws_size,
                              hipStream_t stream) {
    const float* x  = (const float*)d_in[0];
    const float* cb = (const float*)d_in[1];
    float* out = (float*)d_out;
    float* Bt  = (float*)d_ws;                 // 768 floats
    float* cbT = (float*)d_ws + 1024;          // 98304 floats (384 KB)
    rvq_prep<<<384, 256, 0, stream>>>(cb, Bt, cbT);
    // 16384 waves (one 16-item batch each) = 4096 blocks x 4 waves
    rvq_kernel<<<kItems / (kBatch * 4), kBlock, 0, stream>>>(x, cb, Bt, cbT, out);
}

// Round 20
// 1154.265 us; speedup vs baseline: 2.1089x; 1.5538x over previous
//
#include <hip/hip_runtime.h>
#include <math.h>

// Residual VQ: x (262144,128) fp32, codebooks (3,256,128) fp32.
// Output: [indices as float (262144*3)] ++ [quantized (262144*128)].
//
// ARITHMETIC CONTRACT (absmax=0 — do not change):
//   M_k  = OpenBLAS sgemm K-loop: sequential FMA chain j=0..127, acc init 0
//   A    = np.sum(r*r): pairwise_sum 8-accumulator scheme, products rounded
//          separately (fmaf(x,x,0) = single-rounded product, blocks fusion)
//   d2_k = (A - 2.0f*M_k) + B_k ; argmin strict < ascending k == first-min
//          (per-lane v-ascending strict-<, then (val,idx) shuffle-reduce
//           with tie -> smaller idx: identical semantics)
//   residual: r1 = x - q0, r2 = r1 - q1 — in-place global scratch, ref order
//   quantized = (q0 + q1) + q2 elementwise fp32, ref order
//
// ROUND 24 CHANGE: r23 found the HW occupancy cliff (VGPR>128 -> waves/SIMD
// halve, m69 granularity 64/128/256) — the whole working set must stay <=128.
// Revised stall model for r20 (VALUBusy 40% at ~1.8 waves/SIMD = 20% duty =
// ~2000cyc stall per 512cyc phase): the per-phase cb load (~200cyc) can't do
// that, but the 16 MITEM broadcast rv loads CAN — each is consumed
// immediately by its 16 dependent FMAs (no hoisting at VGPR 108: only ~20
// spare regs), so 16 x (120cyc L1 + 32cyc issue) ~= 2400cyc/phase -> 21%
// duty -> 40% VALUBusy. Matches exactly. Fix: (a) 5-deep named rv ring
// (rv0..rv4, +20 VGPR): item i's FMAs cover items i+1..i+4's loads in
// flight (128 FMA-cyc cover >= 120cyc latency); (b) cb tile re-layout
// (d-innermost) so the 16 per-phase cb dwords become 4 coalesced float4
// loads (same values/regs, 12 fewer VMEM issues, same FMA order). Budget
// 64 acc + 16 cb + 20 rv + ~15 misc ~= 115 < 128. Hint stays (256,2).
// Bit-exact: identical loads' values, identical chain order (verified r20).

constexpr int kItems = 262144;
constexpr int kDim   = 128;
constexpr int kNcb   = 3;
constexpr int kK     = 256;
constexpr int kBlock = 256;
constexpr int kBatch = 16;        // items per wave (wave-private batch)
constexpr int NPH    = 32;        // phases of 4 dims

__device__ __forceinline__ float sq_rn(float x) {
    return __builtin_fmaf(x, x, 0.0f);
}

// numpy pairwise_sum, n=128 (for the B-table)
template <typename F>
__device__ __forceinline__ float np_pairwise128(F term) {
    float r0 = term(0), r1 = term(1), r2 = term(2), r3 = term(3),
          r4 = term(4), r5 = term(5), r6 = term(6), r7 = term(7);
    #pragma unroll
    for (int i = 8; i < 128; i += 8) {
        r0 = r0 + term(i + 0); r1 = r1 + term(i + 1);
        r2 = r2 + term(i + 2); r3 = r3 + term(i + 3);
        r4 = r4 + term(i + 4); r5 = r5 + term(i + 5);
        r6 = r6 + term(i + 6); r7 = r7 + term(i + 7);
    }
    return ((r0 + r1) + (r2 + r3)) + ((r4 + r5) + (r6 + r7));
}

// ---------- pre-kernel: Bt (768 floats) + phase-major codebook cbT2:
// cbT2[(((c*32+p)*4 + v)*64 + l)*4 + d] = cb[(c*256 + 64v+l)*128 + 4p+d]
// -> per (phase, v), lane l loads ONE coalesced float4 = its 4 dims.
__global__ void rvq_prep(const float* __restrict__ cb,
                         float* __restrict__ Bt,
                         float* __restrict__ cbT2)
{
    const int tid = blockIdx.x * 256 + threadIdx.x;   // 384*256 = 98304
    const int d = tid & 3;
    const int l = (tid >> 2) & 63;
    const int v = (tid >> 8) & 3;
    const int p = (tid >> 10) & 31;
    const int c = tid >> 15;
    cbT2[tid] = cb[((size_t)c * kK + 64 * v + l) * kDim + (4 * p + d)];
    if (tid < kNcb * kK) {
        const float* row = cb + (size_t)tid * kDim;
        Bt[tid] = np_pairwise128([&](int jj) { return sq_rn(row[jj]); });
    }
}

#define X16(X) X(0) X(1) X(2) X(3) X(4) X(5) X(6) X(7) \
  X(8) X(9) X(10) X(11) X(12) X(13) X(14) X(15)

#define MDECL(i) float m##i##_0 = 0.f, m##i##_1 = 0.f, \
                       m##i##_2 = 0.f, m##i##_3 = 0.f;

// 16 FMAs for item i using its broadcast residual RV and the cb tile
// q0..q3 (q_v = dims 4p..4p+3 of entry 64v+lane). Per-acc chain order:
// d ascending within phase, phases ascending -> j=0..127 sequential
// (OpenBLAS K order; q_v.x==cb0_v etc., identical to r20 bit-for-bit).
#define FMAS(i, RV) \
    m##i##_0 = __builtin_fmaf(RV.x, q0.x, m##i##_0); \
    m##i##_0 = __builtin_fmaf(RV.y, q0.y, m##i##_0); \
    m##i##_0 = __builtin_fmaf(RV.z, q0.z, m##i##_0); \
    m##i##_0 = __builtin_fmaf(RV.w, q0.w, m##i##_0); \
    m##i##_1 = __builtin_fmaf(RV.x, q1.x, m##i##_1); \
    m##i##_1 = __builtin_fmaf(RV.y, q1.y, m##i##_1); \
    m##i##_1 = __builtin_fmaf(RV.z, q1.z, m##i##_1); \
    m##i##_1 = __builtin_fmaf(RV.w, q1.w, m##i##_1); \
    m##i##_2 = __builtin_fmaf(RV.x, q2.x, m##i##_2); \
    m##i##_2 = __builtin_fmaf(RV.y, q2.y, m##i##_2); \
    m##i##_2 = __builtin_fmaf(RV.z, q2.z, m##i##_2); \
    m##i##_2 = __builtin_fmaf(RV.w, q2.w, m##i##_2); \
    m##i##_3 = __builtin_fmaf(RV.x, q3.x, m##i##_3); \
    m##i##_3 = __builtin_fmaf(RV.y, q3.y, m##i##_3); \
    m##i##_3 = __builtin_fmaf(RV.z, q3.z, m##i##_3); \
    m##i##_3 = __builtin_fmaf(RV.w, q3.w, m##i##_3);

// pipeline steps: FMAs for item i on ring slot r, then refill slot r with
// item i+5's residual (in flight across the next 4 items' FMAs = 128cyc)
#define MSTEPL(i, r) { FMAS(i, rv##r) \
    rv##r = *(const float4*)(rb_ + (size_t)((i) + 5) * kDim + 4 * p); }
#define MSTEPN(i, r) { FMAS(i, rv##r) }

// d2 + argmin for item i (strict <, v ascending, then butterfly; tie ->
// smaller idx == numpy first-min over all 256 entries)
#define ARGMIN(i) { \
    const float Ai = __shfl(Areg, (i)); \
    float bv = __builtin_fmaf(-2.0f, m##i##_0, Ai) + B0; \
    int   bx = lane; \
    float dd = __builtin_fmaf(-2.0f, m##i##_1, Ai) + B1; \
    if (dd < bv) { bv = dd; bx = 64 + lane; } \
    dd = __builtin_fmaf(-2.0f, m##i##_2, Ai) + B2; \
    if (dd < bv) { bv = dd; bx = 128 + lane; } \
    dd = __builtin_fmaf(-2.0f, m##i##_3, Ai) + B3; \
    if (dd < bv) { bv = dd; bx = 192 + lane; } \
    _Pragma("unroll") \
    for (int off = 32; off; off >>= 1) { \
        const float ov = __shfl_xor(bv, off); \
        const int   ox = __shfl_xor(bx, off); \
        const bool take = (ov < bv) || (ov == bv && ox < bx); \
        bv = take ? ov : bv; bx = take ? ox : bx; \
    } \
    if (c == 0)      sel0 = (lane == (i)) ? bx : sel0; \
    else if (c == 1) sel1 = (lane == (i)) ? bx : sel1; \
    else             sel2 = (lane == (i)) ? bx : sel2; }

__global__ __launch_bounds__(kBlock, 2) void rvq_kernel(
    const float* __restrict__ x,
    const float* __restrict__ cb,
    const float* __restrict__ Bt,
    const float* __restrict__ cbT2,
    float* __restrict__ out)
{
    const int t = threadIdx.x;
    const int lane = t & 63;
    // global wave id = batch id; each wave fully independent (no LDS, no bar)
    const int wid = blockIdx.x * (kBlock / 64) + (t >> 6);
    const size_t ibase = (size_t)wid * kBatch;

    float* out_idx = out;                             // (items, 3) as float
    float* out_q   = out + (size_t)kItems * kNcb;     // (items, 128)

    const float* xb = x + ibase * kDim;               // batch x rows
    float*       qb = out_q + ibase * kDim;           // batch scratch rows

    int sel0 = 0, sel1 = 0, sel2 = 0;                 // lane i: item i's sel

    #pragma unroll 1
    for (int c = 0; c < kNcb; ++c) {
        const float* rb_ = (c == 0) ? xb : (const float*)qb;
        const float* cbTc = cbT2 + (size_t)c * 32768;  // 32 phases*4v*64l*4d

        // ---- A: lane i computes item i's np.sum(r*r), 8-stripe pairwise
        float Areg = 0.0f;
        if (lane < kBatch) {
            const float4* rr = (const float4*)(rb_ + (size_t)lane * kDim);
            float4 ra = rr[0], rb2 = rr[1];
            float a0 = sq_rn(ra.x),  a1 = sq_rn(ra.y),
                  a2 = sq_rn(ra.z),  a3 = sq_rn(ra.w),
                  a4 = sq_rn(rb2.x), a5 = sq_rn(rb2.y),
                  a6 = sq_rn(rb2.z), a7 = sq_rn(rb2.w);
            #pragma unroll
            for (int g = 1; g < 16; ++g) {
                ra = rr[2 * g]; rb2 = rr[2 * g + 1];
                a0 = a0 + sq_rn(ra.x);  a1 = a1 + sq_rn(ra.y);
                a2 = a2 + sq_rn(ra.z);  a3 = a3 + sq_rn(ra.w);
                a4 = a4 + sq_rn(rb2.x); a5 = a5 + sq_rn(rb2.y);
                a6 = a6 + sq_rn(rb2.z); a7 = a7 + sq_rn(rb2.w);
            }
            Areg = ((a0 + a1) + (a2 + a3)) + ((a4 + a5) + (a6 + a7));
        }

        // ---- M: 64 accs (16 items x 4 entry-groups); cb tile = 4 coalesced
        // float4 loads/phase; rv broadcasts on a 5-deep prefetch ring
        X16(MDECL)
        #pragma unroll 1
        for (int p = 0; p < NPH; ++p) {
            const float4* cbq = (const float4*)(cbTc + ((size_t)p * 4) * 256)
                                + lane;
            const float4 q0 = cbq[0];          // v=0: entries   0+lane
            const float4 q1 = cbq[64];         // v=1: entries  64+lane
            const float4 q2 = cbq[128];        // v=2: entries 128+lane
            const float4 q3 = cbq[192];        // v=3: entries 192+lane

            float4 rv0 = *(const float4*)(rb_ + 0 * kDim + 4 * p);
            float4 rv1 = *(const float4*)(rb_ + 1 * kDim + 4 * p);
            float4 rv2 = *(const float4*)(rb_ + 2 * kDim + 4 * p);
            float4 rv3 = *(const float4*)(rb_ + 3 * kDim + 4 * p);
            float4 rv4 = *(const float4*)(rb_ + 4 * kDim + 4 * p);

            MSTEPL(0, 0)  MSTEPL(1, 1)  MSTEPL(2, 2)  MSTEPL(3, 3)
            MSTEPL(4, 4)  MSTEPL(5, 0)  MSTEPL(6, 1)  MSTEPL(7, 2)
            MSTEPL(8, 3)  MSTEPL(9, 4)  MSTEPL(10, 0)
            MSTEPN(11, 1) MSTEPN(12, 2) MSTEPN(13, 3)
            MSTEPN(14, 4) MSTEPN(15, 0)
        }

        // ---- argmin (B per-lane, coalesced)
        const float* Btc = Bt + c * kK;
        const float B0 = Btc[lane],       B1 = Btc[64 + lane];
        const float B2 = Btc[128 + lane], B3 = Btc[192 + lane];
        X16(ARGMIN)

        // ---- residual update into wave-private scratch rows
        if (c < 2) {
            #pragma unroll 1
            for (int i = 0; i < kBatch; ++i) {
                const int s = __shfl((c == 0) ? sel0 : sel1, i);
                const float* cwrow = cb + ((size_t)c * kK + s) * kDim;
                const float2 w = *(const float2*)(cwrow + 2 * lane);
                float* dr = qb + (size_t)i * kDim;
                const float* sr = (c == 0) ? (xb + (size_t)i * kDim)
                                           : (const float*)dr;
                float2 rv = *(const float2*)(sr + 2 * lane);
                rv.x = rv.x - w.x;             // one rounding each, ref order
                rv.y = rv.y - w.y;
                *(float2*)(dr + 2 * lane) = rv;
            }
            // scratch writes must be visible to this wave's next-cb loads
            asm volatile("s_waitcnt vmcnt(0)" ::: "memory");
        }
    }

    // ---- outputs: quantized (overwrites scratch; all r2 reads done) + idx
    #pragma unroll 1
    for (int i = 0; i < kBatch; ++i) {
        const int s0 = __shfl(sel0, i);
        const int s1 = __shfl(sel1, i);
        const int s2 = __shfl(sel2, i);
        const float2 u = *(const float2*)(cb + ((size_t)0 * kK + s0) * kDim + 2 * lane);
        const float2 v = *(const float2*)(cb + ((size_t)1 * kK + s1) * kDim + 2 * lane);
        const float2 w = *(const float2*)(cb + ((size_t)2 * kK + s2) * kDim + 2 * lane);
        float2 o;
        o.x = (u.x + v.x) + w.x;               // ((0+q0)+q1)+q2, ref order
        o.y = (u.y + v.y) + w.y;
        *(float2*)(qb + (size_t)i * kDim + 2 * lane) = o;
        if (lane == 0) {
            out_idx[(ibase + i) * kNcb + 0] = (float)s0;
            out_idx[(ibase + i) * kNcb + 1] = (float)s1;
            out_idx[(ibase + i) * kNcb + 2] = (float)s2;
        }
    }
}

extern "C" void kernel_launch(void* const* d_in, const int* in_sizes, int n_in,
                              void* d_out, int out_size, void* d_ws, size_t ws_size,
                              hipStream_t stream) {
    const float* x  = (const float*)d_in[0];
    const float* cb = (const float*)d_in[1];
    float* out = (float*)d_out;
    float* Bt  = (float*)d_ws;                 // 768 floats
    float* cbT2 = (float*)d_ws + 1024;         // 98304 floats (384 KB)
    rvq_prep<<<384, 256, 0, stream>>>(cb, Bt, cbT2);
    // 16384 waves (one 16-item batch each) = 4096 blocks x 4 waves
    rvq_kernel<<<kItems / (kBatch * 4), kBlock, 0, stream>>>(x, cb, Bt, cbT2, out);
}

// Round 22
// 702.373 us; speedup vs baseline: 3.4657x; 1.6434x over previous
//
#include <hip/hip_runtime.h>
#include <math.h>

// Residual VQ: x (262144,128) fp32, codebooks (3,256,128) fp32.
// Output: [indices as float (262144*3)] ++ [quantized (262144*128)].
//
// ARITHMETIC CONTRACT (absmax=0 — do not change):
//   M_k  = OpenBLAS sgemm K-loop: sequential FMA chain j=0..127, acc init 0
//   A    = np.sum(r*r): pairwise_sum 8-accumulator scheme, products rounded
//          separately (fmaf(x,x,0) = single-rounded product, blocks fusion)
//   d2_k = (A - 2.0f*M_k) + B_k ; argmin strict < ascending k == first-min
//          (per-lane v-ascending strict-<, then (val,idx) shuffle-reduce
//           with tie -> smaller idx: identical semantics)
//   residual: r1 = x - q0, r2 = r1 - q1 — in-place global scratch, ref order
//   quantized = (q0 + q1) + q2 elementwise fp32, ref order
//
// ROUND 26 CHANGE: r25's compile failed because the s_load base "s"
// constraint bound to a VGPR pair — the residual pointer flows through a
// per-wave select, so divergence analysis couldn't prove it uniform. Fix
// (HK technique: readfirstlane-hoist bases to SGPR): readfirstlane both
// 32-bit halves of the per-phase base — semantically a no-op (the value IS
// wave-uniform) but makes uniformity provable, so "s" binds an SGPR pair.
// Theory unchanged: the rv stream is wave-uniform -> move it off the
// VGPR-starved vector path (64 live accs leave ~5 loads in flight ->
// ~3750cyc/phase serialization, VALUBusy 40%) into the IDLE SGPR file:
// 16 s_load_dwordx4/phase all in flight concurrently, one amortized lgkm
// latency, zero VGPR cost; FMAs take rv as the legal 1-SGPR operand.
// q-loads (VMEM) issue before the asm, land under the lgkm wait.
// COHERENCE: scalar K$ not coherent with vector writes -> vmcnt(0) +
// s_dcache_inv after each residual update (scratch is wave-private; only
// rv s_loads use K$; c=0 reads only x). Same addresses/values/chain order.

constexpr int kItems = 262144;
constexpr int kDim   = 128;
constexpr int kNcb   = 3;
constexpr int kK     = 256;
constexpr int kBlock = 256;
constexpr int kBatch = 16;        // items per wave (wave-private batch)
constexpr int NPH    = 32;        // phases of 4 dims

typedef float sf4 __attribute__((ext_vector_type(4)));

__device__ __forceinline__ float sq_rn(float x) {
    return __builtin_fmaf(x, x, 0.0f);
}

// numpy pairwise_sum, n=128 (for the B-table)
template <typename F>
__device__ __forceinline__ float np_pairwise128(F term) {
    float r0 = term(0), r1 = term(1), r2 = term(2), r3 = term(3),
          r4 = term(4), r5 = term(5), r6 = term(6), r7 = term(7);
    #pragma unroll
    for (int i = 8; i < 128; i += 8) {
        r0 = r0 + term(i + 0); r1 = r1 + term(i + 1);
        r2 = r2 + term(i + 2); r3 = r3 + term(i + 3);
        r4 = r4 + term(i + 4); r5 = r5 + term(i + 5);
        r6 = r6 + term(i + 6); r7 = r7 + term(i + 7);
    }
    return ((r0 + r1) + (r2 + r3)) + ((r4 + r5) + (r6 + r7));
}

// ---------- pre-kernel: Bt (768 floats) + phase-major codebook cbT2:
// cbT2[(((c*32+p)*4 + v)*64 + l)*4 + d] = cb[(c*256 + 64v+l)*128 + 4p+d]
// -> per (phase, v), lane l loads ONE coalesced float4 = its 4 dims.
__global__ void rvq_prep(const float* __restrict__ cb,
                         float* __restrict__ Bt,
                         float* __restrict__ cbT2)
{
    const int tid = blockIdx.x * 256 + threadIdx.x;   // 384*256 = 98304
    const int d = tid & 3;
    const int l = (tid >> 2) & 63;
    const int v = (tid >> 8) & 3;
    const int p = (tid >> 10) & 31;
    const int c = tid >> 15;
    cbT2[tid] = cb[((size_t)c * kK + 64 * v + l) * kDim + (4 * p + d)];
    if (tid < kNcb * kK) {
        const float* row = cb + (size_t)tid * kDim;
        Bt[tid] = np_pairwise128([&](int jj) { return sq_rn(row[jj]); });
    }
}

#define X16(X) X(0) X(1) X(2) X(3) X(4) X(5) X(6) X(7) \
  X(8) X(9) X(10) X(11) X(12) X(13) X(14) X(15)

#define MDECL(i) float m##i##_0 = 0.f, m##i##_1 = 0.f, \
                       m##i##_2 = 0.f, m##i##_3 = 0.f;

// 16 FMAs for item i: RV components are SGPR scalars (1 SGPR operand per
// v_fma — legal); q0..q3 are the VGPR cb tile (q_v = dims 4p..4p+3 of entry
// 64v+lane). Per-acc chain: d ascending within phase, phases ascending ->
// j=0..127 sequential (OpenBLAS K order, bit-exact, identical to r20/r24).
#define FMAS(i, RV) \
    m##i##_0 = __builtin_fmaf(RV.x, q0.x, m##i##_0); \
    m##i##_0 = __builtin_fmaf(RV.y, q0.y, m##i##_0); \
    m##i##_0 = __builtin_fmaf(RV.z, q0.z, m##i##_0); \
    m##i##_0 = __builtin_fmaf(RV.w, q0.w, m##i##_0); \
    m##i##_1 = __builtin_fmaf(RV.x, q1.x, m##i##_1); \
    m##i##_1 = __builtin_fmaf(RV.y, q1.y, m##i##_1); \
    m##i##_1 = __builtin_fmaf(RV.z, q1.z, m##i##_1); \
    m##i##_1 = __builtin_fmaf(RV.w, q1.w, m##i##_1); \
    m##i##_2 = __builtin_fmaf(RV.x, q2.x, m##i##_2); \
    m##i##_2 = __builtin_fmaf(RV.y, q2.y, m##i##_2); \
    m##i##_2 = __builtin_fmaf(RV.z, q2.z, m##i##_2); \
    m##i##_2 = __builtin_fmaf(RV.w, q2.w, m##i##_2); \
    m##i##_3 = __builtin_fmaf(RV.x, q3.x, m##i##_3); \
    m##i##_3 = __builtin_fmaf(RV.y, q3.y, m##i##_3); \
    m##i##_3 = __builtin_fmaf(RV.z, q3.z, m##i##_3); \
    m##i##_3 = __builtin_fmaf(RV.w, q3.w, m##i##_3);

#define RVDECL(i) sf4 rv##i;
#define DOFMA(i)  FMAS(i, rv##i)

// d2 + argmin for item i (strict <, v ascending, then butterfly; tie ->
// smaller idx == numpy first-min over all 256 entries)
#define ARGMIN(i) { \
    const float Ai = __shfl(Areg, (i)); \
    float bv = __builtin_fmaf(-2.0f, m##i##_0, Ai) + B0; \
    int   bx = lane; \
    float dd = __builtin_fmaf(-2.0f, m##i##_1, Ai) + B1; \
    if (dd < bv) { bv = dd; bx = 64 + lane; } \
    dd = __builtin_fmaf(-2.0f, m##i##_2, Ai) + B2; \
    if (dd < bv) { bv = dd; bx = 128 + lane; } \
    dd = __builtin_fmaf(-2.0f, m##i##_3, Ai) + B3; \
    if (dd < bv) { bv = dd; bx = 192 + lane; } \
    _Pragma("unroll") \
    for (int off = 32; off; off >>= 1) { \
        const float ov = __shfl_xor(bv, off); \
        const int   ox = __shfl_xor(bx, off); \
        const bool take = (ov < bv) || (ov == bv && ox < bx); \
        bv = take ? ov : bv; bx = take ? ox : bx; \
    } \
    if (c == 0)      sel0 = (lane == (i)) ? bx : sel0; \
    else if (c == 1) sel1 = (lane == (i)) ? bx : sel1; \
    else             sel2 = (lane == (i)) ? bx : sel2; }

__global__ __launch_bounds__(kBlock, 2) void rvq_kernel(
    const float* __restrict__ x,
    const float* __restrict__ cb,
    const float* __restrict__ Bt,
    const float* __restrict__ cbT2,
    float* __restrict__ out)
{
    const int t = threadIdx.x;
    const int lane = t & 63;
    // global wave id = batch id; each wave fully independent (no LDS, no bar)
    const int wid = blockIdx.x * (kBlock / 64) + (t >> 6);
    const size_t ibase = (size_t)wid * kBatch;

    float* out_idx = out;                             // (items, 3) as float
    float* out_q   = out + (size_t)kItems * kNcb;     // (items, 128)

    const float* xb = x + ibase * kDim;               // batch x rows
    float*       qb = out_q + ibase * kDim;           // batch scratch rows

    int sel0 = 0, sel1 = 0, sel2 = 0;                 // lane i: item i's sel

    #pragma unroll 1
    for (int c = 0; c < kNcb; ++c) {
        const float* rb_ = (c == 0) ? xb : (const float*)qb;
        const float* cbTc = cbT2 + (size_t)c * 32768;  // 32 phases*4v*64l*4d

        // uniform SGPR base for the rv s_loads: readfirstlane both halves
        // (value IS wave-uniform; this makes it PROVABLY uniform so the
        // "s" constraint binds an SGPR pair instead of failing to VGPRs)
        const uint64_t rbu = (uint64_t)(const void*)rb_;
        const uint32_t blo = __builtin_amdgcn_readfirstlane((uint32_t)rbu);
        const uint32_t bhi = __builtin_amdgcn_readfirstlane((uint32_t)(rbu >> 32));
        const uint64_t sbase = ((uint64_t)bhi << 32) | (uint64_t)blo;

        // ---- A: lane i computes item i's np.sum(r*r), 8-stripe pairwise
        // (vector path — per-lane rows, coherent with the vector stores)
        float Areg = 0.0f;
        if (lane < kBatch) {
            const float4* rr = (const float4*)(rb_ + (size_t)lane * kDim);
            float4 ra = rr[0], rb2v = rr[1];
            float a0 = sq_rn(ra.x),   a1 = sq_rn(ra.y),
                  a2 = sq_rn(ra.z),   a3 = sq_rn(ra.w),
                  a4 = sq_rn(rb2v.x), a5 = sq_rn(rb2v.y),
                  a6 = sq_rn(rb2v.z), a7 = sq_rn(rb2v.w);
            #pragma unroll
            for (int g = 1; g < 16; ++g) {
                ra = rr[2 * g]; rb2v = rr[2 * g + 1];
                a0 = a0 + sq_rn(ra.x);   a1 = a1 + sq_rn(ra.y);
                a2 = a2 + sq_rn(ra.z);   a3 = a3 + sq_rn(ra.w);
                a4 = a4 + sq_rn(rb2v.x); a5 = a5 + sq_rn(rb2v.y);
                a6 = a6 + sq_rn(rb2v.z); a7 = a7 + sq_rn(rb2v.w);
            }
            Areg = ((a0 + a1) + (a2 + a3)) + ((a4 + a5) + (a6 + a7));
        }

        // ---- M: 64 accs (16 items x 4 entry-groups); cb tile = 4 coalesced
        // float4 VMEM loads/phase; rv stream = 16 s_load_dwordx4 into SGPRs
        X16(MDECL)
        #pragma unroll 1
        for (int p = 0; p < NPH; ++p) {
            // q loads first: in flight during the lgkm wait below
            const float4* cbq = (const float4*)(cbTc + ((size_t)p * 4) * 256)
                                + lane;
            const float4 q0 = cbq[0];          // v=0: entries   0+lane
            const float4 q1 = cbq[64];         // v=1: entries  64+lane
            const float4 q2 = cbq[128];        // v=2: entries 128+lane
            const float4 q3 = cbq[192];        // v=3: entries 192+lane

            const uint64_t sb = sbase + (uint64_t)(16 * p);  // uniform base
            X16(RVDECL)
            asm volatile(
                "s_load_dwordx4 %[r0],  %[b], 0x0\n\t"
                "s_load_dwordx4 %[r1],  %[b], 0x200\n\t"
                "s_load_dwordx4 %[r2],  %[b], 0x400\n\t"
                "s_load_dwordx4 %[r3],  %[b], 0x600\n\t"
                "s_load_dwordx4 %[r4],  %[b], 0x800\n\t"
                "s_load_dwordx4 %[r5],  %[b], 0xa00\n\t"
                "s_load_dwordx4 %[r6],  %[b], 0xc00\n\t"
                "s_load_dwordx4 %[r7],  %[b], 0xe00\n\t"
                "s_load_dwordx4 %[r8],  %[b], 0x1000\n\t"
                "s_load_dwordx4 %[r9],  %[b], 0x1200\n\t"
                "s_load_dwordx4 %[r10], %[b], 0x1400\n\t"
                "s_load_dwordx4 %[r11], %[b], 0x1600\n\t"
                "s_load_dwordx4 %[r12], %[b], 0x1800\n\t"
                "s_load_dwordx4 %[r13], %[b], 0x1a00\n\t"
                "s_load_dwordx4 %[r14], %[b], 0x1c00\n\t"
                "s_load_dwordx4 %[r15], %[b], 0x1e00\n\t"
                "s_waitcnt lgkmcnt(0)"
                : [r0]"=s"(rv0),  [r1]"=s"(rv1),  [r2]"=s"(rv2),
                  [r3]"=s"(rv3),  [r4]"=s"(rv4),  [r5]"=s"(rv5),
                  [r6]"=s"(rv6),  [r7]"=s"(rv7),  [r8]"=s"(rv8),
                  [r9]"=s"(rv9),  [r10]"=s"(rv10), [r11]"=s"(rv11),
                  [r12]"=s"(rv12), [r13]"=s"(rv13), [r14]"=s"(rv14),
                  [r15]"=s"(rv15)
                : [b]"s"(sb)
                : "memory");

            X16(DOFMA)
        }

        // ---- argmin (B per-lane, coalesced)
        const float* Btc = Bt + c * kK;
        const float B0 = Btc[lane],       B1 = Btc[64 + lane];
        const float B2 = Btc[128 + lane], B3 = Btc[192 + lane];
        X16(ARGMIN)

        // ---- residual update into wave-private scratch rows (vector)
        if (c < 2) {
            #pragma unroll 1
            for (int i = 0; i < kBatch; ++i) {
                const int s = __shfl((c == 0) ? sel0 : sel1, i);
                const float* cwrow = cb + ((size_t)c * kK + s) * kDim;
                const float2 w = *(const float2*)(cwrow + 2 * lane);
                float* dr = qb + (size_t)i * kDim;
                const float* sr = (c == 0) ? (xb + (size_t)i * kDim)
                                           : (const float*)dr;
                float2 rv = *(const float2*)(sr + 2 * lane);
                rv.x = rv.x - w.x;             // one rounding each, ref order
                rv.y = rv.y - w.y;
                *(float2*)(dr + 2 * lane) = rv;
            }
            // drain vector writes to L2, then invalidate the scalar K$ so
            // the next codebook's s_loads observe the fresh residuals
            asm volatile("s_waitcnt vmcnt(0)" ::: "memory");
            __builtin_amdgcn_s_dcache_inv();
        }
    }

    // ---- outputs: quantized (overwrites scratch; all r2 reads done) + idx
    #pragma unroll 1
    for (int i = 0; i < kBatch; ++i) {
        const int s0 = __shfl(sel0, i);
        const int s1 = __shfl(sel1, i);
        const int s2 = __shfl(sel2, i);
        const float2 u = *(const float2*)(cb + ((size_t)0 * kK + s0) * kDim + 2 * lane);
        const float2 v = *(const float2*)(cb + ((size_t)1 * kK + s1) * kDim + 2 * lane);
        const float2 w = *(const float2*)(cb + ((size_t)2 * kK + s2) * kDim + 2 * lane);
        float2 o;
        o.x = (u.x + v.x) + w.x;               // ((0+q0)+q1)+q2, ref order
        o.y = (u.y + v.y) + w.y;
        *(float2*)(qb + (size_t)i * kDim + 2 * lane) = o;
        if (lane == 0) {
            out_idx[(ibase + i) * kNcb + 0] = (float)s0;
            out_idx[(ibase + i) * kNcb + 1] = (float)s1;
            out_idx[(ibase + i) * kNcb + 2] = (float)s2;
        }
    }
}

extern "C" void kernel_launch(void* const* d_in, const int* in_sizes, int n_in,
                              void* d_out, int out_size, void* d_ws, size_t ws_size,
                              hipStream_t stream) {
    const float* x  = (const float*)d_in[0];
    const float* cb = (const float*)d_in[1];
    float* out = (float*)d_out;
    float* Bt  = (float*)d_ws;                 // 768 floats
    float* cbT2 = (float*)d_ws + 1024;         // 98304 floats (384 KB)
    rvq_prep<<<384, 256, 0, stream>>>(cb, Bt, cbT2);
    // 16384 waves (one 16-item batch each) = 4096 blocks x 4 waves
    rvq_kernel<<<kItems / (kBatch * 4), kBlock, 0, stream>>>(x, cb, Bt, cbT2, out);
}